// Round 1
// baseline (519.079 us; speedup 1.0000x reference)
//
#include <hip/hip_runtime.h>
#include <hip/hip_bf16.h>

// GCN: 3 layers of (X @ W) -> symmetric-normalized neighbor aggregation (+self loop) -> bias -> relu
// N=50000 nodes, E=640000 edges, dims 256 -> 128 -> 128 -> 16, all fp32.
// Strategy: build CSR by dst each launch (count/scan/fill), pull-aggregate (no atomics in hot path).

#define NFEAT_IN 256
#define HIDDEN   128
#define NCLS     16

// ---------------- CSR build ----------------

__global__ void count_kernel(const int* __restrict__ dst, int* __restrict__ cnt, int E) {
    int e = blockIdx.x * 256 + threadIdx.x;
    if (e < E) atomicAdd(&cnt[dst[e]], 1);
}

__global__ void scan_kernel(const int* __restrict__ cnt, int* __restrict__ row_ptr, int N) {
    __shared__ int sums[1024];
    const int t = threadIdx.x;
    const int ipt = (N + 1023) / 1024;
    const int start = t * ipt;
    int s = 0;
    for (int i = 0; i < ipt; i++) {
        int idx = start + i;
        if (idx < N) s += cnt[idx];
    }
    sums[t] = s;
    __syncthreads();
    // Hillis-Steele inclusive scan over 1024 partials
    for (int off = 1; off < 1024; off <<= 1) {
        int v = (t >= off) ? sums[t - off] : 0;
        __syncthreads();
        sums[t] += v;
        __syncthreads();
    }
    int run = (t == 0) ? 0 : sums[t - 1];
    for (int i = 0; i < ipt; i++) {
        int idx = start + i;
        if (idx < N) { row_ptr[idx] = run; run += cnt[idx]; }
    }
    if (t == 1023) row_ptr[N] = sums[1023];
}

__global__ void dis_kernel(const int* __restrict__ cnt, float* __restrict__ dis, int N) {
    int i = blockIdx.x * 256 + threadIdx.x;
    if (i < N) dis[i] = rsqrtf((float)(cnt[i] + 1));  // +1 = self loop; deg >= 1 always
}

__global__ void fill_kernel(const int* __restrict__ src, const int* __restrict__ dst,
                            const float* __restrict__ dis, const int* __restrict__ row_ptr,
                            int* __restrict__ cursor, int* __restrict__ ssrc,
                            float* __restrict__ sw, int E) {
    int e = blockIdx.x * 256 + threadIdx.x;
    if (e >= E) return;
    int s = src[e], d = dst[e];
    int pos = atomicAdd(&cursor[d], 1);
    int idx = row_ptr[d] + pos;
    ssrc[idx] = s;
    sw[idx] = dis[s] * dis[d];
}

// ---------------- GEMM: C[M x 128] = A[M x K] * B[K x 128] ----------------
// BM=64 BN=128 BK=16, 256 threads, thread tile 8x4.

template<int K>
__global__ __launch_bounds__(256) void gemm_n128(const float* __restrict__ A,
                                                 const float* __restrict__ B,
                                                 float* __restrict__ C, int M) {
    constexpr int BM = 64, BN = 128, BK = 16;
    __shared__ float As[BK][BM];   // k-major (transposed on load)
    __shared__ float Bs[BK][BN];
    const int tid = threadIdx.x;
    const int m0 = blockIdx.x * BM;
    const int rg = tid >> 5;          // 0..7 row group (8 rows each)
    const int cg = tid & 31;          // 0..31 col group (4 cols each)
    const int lrow = tid >> 2;        // A-load: row 0..63
    const int lk4  = (tid & 3) * 4;   // A-load: k offset 0/4/8/12

    float acc[8][4] = {};

    for (int kk = 0; kk < K; kk += BK) {
        float4 av = make_float4(0.f, 0.f, 0.f, 0.f);
        if (m0 + lrow < M)
            av = *(const float4*)(A + (size_t)(m0 + lrow) * K + kk + lk4);
        As[lk4 + 0][lrow] = av.x;
        As[lk4 + 1][lrow] = av.y;
        As[lk4 + 2][lrow] = av.z;
        As[lk4 + 3][lrow] = av.w;
#pragma unroll
        for (int t = 0; t < 2; t++) {
            int f4 = tid + t * 256;       // 0..511 float4 id of the 16x128 B tile
            int bk = f4 >> 5;             // 0..15
            int bn = (f4 & 31) * 4;       // 0..124
            float4 bv = *(const float4*)(B + (size_t)(kk + bk) * BN + bn);
            *(float4*)&Bs[bk][bn] = bv;
        }
        __syncthreads();
#pragma unroll
        for (int k = 0; k < BK; k++) {
            float a[8], b[4];
            float4 a0 = *(const float4*)&As[k][rg * 8];
            float4 a1 = *(const float4*)&As[k][rg * 8 + 4];
            float4 bb = *(const float4*)&Bs[k][cg * 4];
            a[0] = a0.x; a[1] = a0.y; a[2] = a0.z; a[3] = a0.w;
            a[4] = a1.x; a[5] = a1.y; a[6] = a1.z; a[7] = a1.w;
            b[0] = bb.x; b[1] = bb.y; b[2] = bb.z; b[3] = bb.w;
#pragma unroll
            for (int i = 0; i < 8; i++)
#pragma unroll
                for (int j = 0; j < 4; j++)
                    acc[i][j] += a[i] * b[j];
        }
        __syncthreads();
    }
#pragma unroll
    for (int i = 0; i < 8; i++) {
        int m = m0 + rg * 8 + i;
        if (m < M)
            *(float4*)(C + (size_t)m * BN + cg * 4) =
                make_float4(acc[i][0], acc[i][1], acc[i][2], acc[i][3]);
    }
}

// GEMM: C[M x 16] = A[M x 128] * B[128 x 16]. 16 rows/block, 256 threads (16x16).
__global__ __launch_bounds__(256) void gemm_n16(const float* __restrict__ A,
                                                const float* __restrict__ B,
                                                float* __restrict__ C, int M) {
    __shared__ float As[16][130];
    __shared__ float Bs[128][16];
    const int tid = threadIdx.x;
    const int m0 = blockIdx.x * 16;
#pragma unroll
    for (int t = 0; t < 2; t++) {
        int f4 = tid + t * 256;   // 0..511 float4 of 16x128 A tile
        int r = f4 >> 5;          // 0..15
        int c4 = (f4 & 31) * 4;
        float4 v = make_float4(0.f, 0.f, 0.f, 0.f);
        if (m0 + r < M) v = *(const float4*)(A + (size_t)(m0 + r) * 128 + c4);
        As[r][c4] = v.x; As[r][c4 + 1] = v.y; As[r][c4 + 2] = v.z; As[r][c4 + 3] = v.w;
        // B tile: 128x16 = 512 float4 as well
        int bk = f4 >> 2;          // 0..127
        int bn = (f4 & 3) * 4;     // 0,4,8,12
        float4 bv = *(const float4*)(B + (size_t)bk * 16 + bn);
        *(float4*)&Bs[bk][bn] = bv;
    }
    __syncthreads();
    const int r = tid >> 4, f = tid & 15;
    float acc = 0.f;
#pragma unroll 8
    for (int k = 0; k < 128; k++) acc += As[r][k] * Bs[k][f];
    if (m0 + r < M) C[(size_t)(m0 + r) * 16 + f] = acc;
}

// ---------------- Aggregation (pull, CSR) ----------------
// One wave per node, 128 features => 2 per lane.
__global__ __launch_bounds__(256) void agg128(const float* __restrict__ T,
                                              const int* __restrict__ row_ptr,
                                              const int* __restrict__ ssrc,
                                              const float* __restrict__ sw,
                                              const float* __restrict__ dis,
                                              const float* __restrict__ bias,
                                              float* __restrict__ Hout, int N, int relu) {
    const int node = (blockIdx.x * 256 + threadIdx.x) >> 6;
    const int lane = threadIdx.x & 63;
    if (node >= N) return;
    const float d = dis[node];
    const float self_w = d * d;
    float acc0 = self_w * T[(size_t)node * 128 + lane];
    float acc1 = self_w * T[(size_t)node * 128 + 64 + lane];
    const int e0 = row_ptr[node], e1 = row_ptr[node + 1];
    for (int e = e0; e < e1; ++e) {
        int s = ssrc[e];
        float w = sw[e];
        acc0 += w * T[(size_t)s * 128 + lane];
        acc1 += w * T[(size_t)s * 128 + 64 + lane];
    }
    acc0 += bias[lane];
    acc1 += bias[64 + lane];
    if (relu) { acc0 = fmaxf(acc0, 0.f); acc1 = fmaxf(acc1, 0.f); }
    Hout[(size_t)node * 128 + lane] = acc0;
    Hout[(size_t)node * 128 + 64 + lane] = acc1;
}

// 16 features: one thread per (node, feat).
__global__ __launch_bounds__(256) void agg16(const float* __restrict__ T,
                                             const int* __restrict__ row_ptr,
                                             const int* __restrict__ ssrc,
                                             const float* __restrict__ sw,
                                             const float* __restrict__ dis,
                                             const float* __restrict__ bias,
                                             float* __restrict__ out, int N) {
    const int t = blockIdx.x * 256 + threadIdx.x;
    const int node = t >> 4;
    const int f = t & 15;
    if (node >= N) return;
    const float d = dis[node];
    float acc = d * d * T[(size_t)node * 16 + f];
    const int e0 = row_ptr[node], e1 = row_ptr[node + 1];
    for (int e = e0; e < e1; ++e) {
        acc += sw[e] * T[(size_t)ssrc[e] * 16 + f];
    }
    out[(size_t)node * 16 + f] = acc + bias[f];
}

// ---------------- launch ----------------

extern "C" void kernel_launch(void* const* d_in, const int* in_sizes, int n_in,
                              void* d_out, int out_size, void* d_ws, size_t ws_size,
                              hipStream_t stream) {
    const float* x  = (const float*)d_in[0];
    const int*   ei = (const int*)d_in[1];
    const float* W1 = (const float*)d_in[2];
    const float* b1 = (const float*)d_in[3];
    const float* W2 = (const float*)d_in[4];
    const float* b2 = (const float*)d_in[5];
    const float* W3 = (const float*)d_in[6];
    const float* b3 = (const float*)d_in[7];
    float* out = (float*)d_out;

    const int N = in_sizes[0] / NFEAT_IN;   // 50000
    const int E = in_sizes[1] / 2;          // 640000
    const int* src = ei;
    const int* dst = ei + E;

    // workspace carve-up (256B aligned)
    char* p = (char*)d_ws;
    auto alloc = [&](size_t bytes) -> void* {
        void* r = (void*)p;
        p += (bytes + 255) & ~(size_t)255;
        return r;
    };
    int*   cnt     = (int*)alloc((size_t)N * 4);
    int*   row_ptr = (int*)alloc(((size_t)N + 1) * 4);
    int*   cursor  = (int*)alloc((size_t)N * 4);
    float* dis     = (float*)alloc((size_t)N * 4);
    int*   ssrc    = (int*)alloc((size_t)E * 4);
    float* sw      = (float*)alloc((size_t)E * 4);
    float* T       = (float*)alloc((size_t)N * 128 * 4);  // pre-agg transform (also reused for T3)
    float* H       = (float*)alloc((size_t)N * 128 * 4);  // post-agg activations

    hipMemsetAsync(cnt, 0, (size_t)N * 4, stream);
    hipMemsetAsync(cursor, 0, (size_t)N * 4, stream);

    const int eb = (E + 255) / 256;
    const int nb = (N + 255) / 256;

    count_kernel<<<eb, 256, 0, stream>>>(dst, cnt, E);
    scan_kernel<<<1, 1024, 0, stream>>>(cnt, row_ptr, N);
    dis_kernel<<<nb, 256, 0, stream>>>(cnt, dis, N);
    fill_kernel<<<eb, 256, 0, stream>>>(src, dst, dis, row_ptr, cursor, ssrc, sw, E);

    const int gemm_blocks = (N + 63) / 64;
    const int agg128_blocks = (N + 3) / 4;     // 4 nodes (waves) per block

    // Layer 1: T = x @ W1 ; H = relu(agg(T) + b1)
    gemm_n128<NFEAT_IN><<<gemm_blocks, 256, 0, stream>>>(x, W1, T, N);
    agg128<<<agg128_blocks, 256, 0, stream>>>(T, row_ptr, ssrc, sw, dis, b1, H, N, 1);

    // Layer 2: T = H @ W2 ; H = relu(agg(T) + b2)
    gemm_n128<HIDDEN><<<gemm_blocks, 256, 0, stream>>>(H, W2, T, N);
    agg128<<<agg128_blocks, 256, 0, stream>>>(T, row_ptr, ssrc, sw, dis, b2, H, N, 1);

    // Layer 3: T3 (reuse T) = H @ W3 ; out = agg(T3) + b3
    gemm_n16<<<(N + 15) / 16, 256, 0, stream>>>(H, W3, T, N);
    agg16<<<(N * 16 + 255) / 256, 256, 0, stream>>>(T, row_ptr, ssrc, sw, dis, b3, out, N);
}

// Round 2
// 430.188 us; speedup vs baseline: 1.2066x; 1.2066x over previous
//
#include <hip/hip_runtime.h>
#include <hip/hip_bf16.h>

// GCN: 3 layers of (X @ W) -> symmetric-normalized neighbor aggregation (+self loop) -> bias -> relu
// N=50000 nodes, E=640000 edges, dims 256 -> 128 -> 128 -> 16, all fp32.
// CSR build per launch (count / 3-kernel scan / fill), pull-aggregation (no atomics in hot path).
// R1: replaced single-block scan_kernel (94 us, latency-bound on 1 CU) with 3-kernel
//     device-wide scan (~7 us) and fused dis computation into scan_final.

#define NFEAT_IN 256
#define HIDDEN   128
#define NCLS     16
#define SCAN_CHUNK 2048   // elements per block in the scan (256 thr x 8)

// ---------------- CSR build ----------------

__global__ void count_kernel(const int* __restrict__ dst, int* __restrict__ cnt, int E) {
    int e = blockIdx.x * 256 + threadIdx.x;
    if (e < E) atomicAdd(&cnt[dst[e]], 1);
}

// Per-chunk sums. grid = nchunks, block = 256, 8 elements/thread coalesced-ish (int stride 32B).
__global__ __launch_bounds__(256) void scan_partial(const int* __restrict__ cnt,
                                                    int* __restrict__ bsum, int N) {
    const int t = threadIdx.x;
    const int base = blockIdx.x * SCAN_CHUNK + t * 8;
    int s = 0;
#pragma unroll
    for (int i = 0; i < 8; i++) {
        int idx = base + i;
        if (idx < N) s += cnt[idx];
    }
#pragma unroll
    for (int off = 32; off > 0; off >>= 1) s += __shfl_down(s, off, 64);
    __shared__ int ws[4];
    if ((t & 63) == 0) ws[t >> 6] = s;
    __syncthreads();
    if (t == 0) bsum[blockIdx.x] = ws[0] + ws[1] + ws[2] + ws[3];
}

// Exclusive scan of <=64 chunk sums in place, one wave.
__global__ void scan_bsum(int* __restrict__ bsum, int nb) {
    const int t = threadIdx.x;
    int orig = (t < nb) ? bsum[t] : 0;
    int v = orig;
#pragma unroll
    for (int off = 1; off < 64; off <<= 1) {
        int u = __shfl_up(v, off, 64);
        if (t >= off) v += u;
    }
    if (t < nb) bsum[t] = v - orig;   // exclusive
}

// Per-chunk exclusive scan + chunk offset -> row_ptr. Also writes dis = rsqrt(deg+1).
__global__ __launch_bounds__(256) void scan_final(const int* __restrict__ cnt,
                                                  const int* __restrict__ bsum,
                                                  int* __restrict__ row_ptr,
                                                  float* __restrict__ dis, int N) {
    const int t = threadIdx.x;
    const int base = blockIdx.x * SCAN_CHUNK + t * 8;
    int v[8];
    int s = 0;
#pragma unroll
    for (int i = 0; i < 8; i++) {
        int idx = base + i;
        v[i] = (idx < N) ? cnt[idx] : 0;
        s += v[i];
    }
    __shared__ int sm[256];
    sm[t] = s;
    __syncthreads();
    for (int off = 1; off < 256; off <<= 1) {
        int u = (t >= off) ? sm[t - off] : 0;
        __syncthreads();
        sm[t] += u;
        __syncthreads();
    }
    int run = bsum[blockIdx.x] + ((t == 0) ? 0 : sm[t - 1]);
#pragma unroll
    for (int i = 0; i < 8; i++) {
        int idx = base + i;
        if (idx < N) {
            row_ptr[idx] = run;
            dis[idx] = rsqrtf((float)(v[i] + 1));   // +1 = self loop; deg >= 1 always
            run += v[i];
            if (idx == N - 1) row_ptr[N] = run;     // total edge count
        }
    }
}

__global__ void fill_kernel(const int* __restrict__ src, const int* __restrict__ dst,
                            const float* __restrict__ dis, const int* __restrict__ row_ptr,
                            int* __restrict__ cursor, int* __restrict__ ssrc,
                            float* __restrict__ sw, int E) {
    int e = blockIdx.x * 256 + threadIdx.x;
    if (e >= E) return;
    int s = src[e], d = dst[e];
    int pos = atomicAdd(&cursor[d], 1);
    int idx = row_ptr[d] + pos;
    ssrc[idx] = s;
    sw[idx] = dis[s] * dis[d];
}

// ---------------- GEMM: C[M x 128] = A[M x K] * B[K x 128] ----------------
// BM=64 BN=128 BK=16, 256 threads, thread tile 8x4.

template<int K>
__global__ __launch_bounds__(256) void gemm_n128(const float* __restrict__ A,
                                                 const float* __restrict__ B,
                                                 float* __restrict__ C, int M) {
    constexpr int BM = 64, BN = 128, BK = 16;
    __shared__ float As[BK][BM];   // k-major (transposed on load)
    __shared__ float Bs[BK][BN];
    const int tid = threadIdx.x;
    const int m0 = blockIdx.x * BM;
    const int rg = tid >> 5;          // 0..7 row group (8 rows each)
    const int cg = tid & 31;          // 0..31 col group (4 cols each)
    const int lrow = tid >> 2;        // A-load: row 0..63
    const int lk4  = (tid & 3) * 4;   // A-load: k offset 0/4/8/12

    float acc[8][4] = {};

    for (int kk = 0; kk < K; kk += BK) {
        float4 av = make_float4(0.f, 0.f, 0.f, 0.f);
        if (m0 + lrow < M)
            av = *(const float4*)(A + (size_t)(m0 + lrow) * K + kk + lk4);
        As[lk4 + 0][lrow] = av.x;
        As[lk4 + 1][lrow] = av.y;
        As[lk4 + 2][lrow] = av.z;
        As[lk4 + 3][lrow] = av.w;
#pragma unroll
        for (int t = 0; t < 2; t++) {
            int f4 = tid + t * 256;       // 0..511 float4 id of the 16x128 B tile
            int bk = f4 >> 5;             // 0..15
            int bn = (f4 & 31) * 4;       // 0..124
            float4 bv = *(const float4*)(B + (size_t)(kk + bk) * BN + bn);
            *(float4*)&Bs[bk][bn] = bv;
        }
        __syncthreads();
#pragma unroll
        for (int k = 0; k < BK; k++) {
            float a[8], b[4];
            float4 a0 = *(const float4*)&As[k][rg * 8];
            float4 a1 = *(const float4*)&As[k][rg * 8 + 4];
            float4 bb = *(const float4*)&Bs[k][cg * 4];
            a[0] = a0.x; a[1] = a0.y; a[2] = a0.z; a[3] = a0.w;
            a[4] = a1.x; a[5] = a1.y; a[6] = a1.z; a[7] = a1.w;
            b[0] = bb.x; b[1] = bb.y; b[2] = bb.z; b[3] = bb.w;
#pragma unroll
            for (int i = 0; i < 8; i++)
#pragma unroll
                for (int j = 0; j < 4; j++)
                    acc[i][j] += a[i] * b[j];
        }
        __syncthreads();
    }
#pragma unroll
    for (int i = 0; i < 8; i++) {
        int m = m0 + rg * 8 + i;
        if (m < M)
            *(float4*)(C + (size_t)m * BN + cg * 4) =
                make_float4(acc[i][0], acc[i][1], acc[i][2], acc[i][3]);
    }
}

// GEMM: C[M x 16] = A[M x 128] * B[128 x 16]. 16 rows/block, 256 threads (16x16).
__global__ __launch_bounds__(256) void gemm_n16(const float* __restrict__ A,
                                                const float* __restrict__ B,
                                                float* __restrict__ C, int M) {
    __shared__ float As[16][130];
    __shared__ float Bs[128][16];
    const int tid = threadIdx.x;
    const int m0 = blockIdx.x * 16;
#pragma unroll
    for (int t = 0; t < 2; t++) {
        int f4 = tid + t * 256;   // 0..511 float4 of 16x128 A tile
        int r = f4 >> 5;          // 0..15
        int c4 = (f4 & 31) * 4;
        float4 v = make_float4(0.f, 0.f, 0.f, 0.f);
        if (m0 + r < M) v = *(const float4*)(A + (size_t)(m0 + r) * 128 + c4);
        As[r][c4] = v.x; As[r][c4 + 1] = v.y; As[r][c4 + 2] = v.z; As[r][c4 + 3] = v.w;
        // B tile: 128x16 = 512 float4 as well
        int bk = f4 >> 2;          // 0..127
        int bn = (f4 & 3) * 4;     // 0,4,8,12
        float4 bv = *(const float4*)(B + (size_t)bk * 16 + bn);
        *(float4*)&Bs[bk][bn] = bv;
    }
    __syncthreads();
    const int r = tid >> 4, f = tid & 15;
    float acc = 0.f;
#pragma unroll 8
    for (int k = 0; k < 128; k++) acc += As[r][k] * Bs[k][f];
    if (m0 + r < M) C[(size_t)(m0 + r) * 16 + f] = acc;
}

// ---------------- Aggregation (pull, CSR) ----------------
// One wave per node, 128 features => 2 per lane.
__global__ __launch_bounds__(256) void agg128(const float* __restrict__ T,
                                              const int* __restrict__ row_ptr,
                                              const int* __restrict__ ssrc,
                                              const float* __restrict__ sw,
                                              const float* __restrict__ dis,
                                              const float* __restrict__ bias,
                                              float* __restrict__ Hout, int N, int relu) {
    const int node = (blockIdx.x * 256 + threadIdx.x) >> 6;
    const int lane = threadIdx.x & 63;
    if (node >= N) return;
    const float d = dis[node];
    const float self_w = d * d;
    float acc0 = self_w * T[(size_t)node * 128 + lane];
    float acc1 = self_w * T[(size_t)node * 128 + 64 + lane];
    const int e0 = row_ptr[node], e1 = row_ptr[node + 1];
    for (int e = e0; e < e1; ++e) {
        int s = ssrc[e];
        float w = sw[e];
        acc0 += w * T[(size_t)s * 128 + lane];
        acc1 += w * T[(size_t)s * 128 + 64 + lane];
    }
    acc0 += bias[lane];
    acc1 += bias[64 + lane];
    if (relu) { acc0 = fmaxf(acc0, 0.f); acc1 = fmaxf(acc1, 0.f); }
    Hout[(size_t)node * 128 + lane] = acc0;
    Hout[(size_t)node * 128 + 64 + lane] = acc1;
}

// 16 features: one thread per (node, feat).
__global__ __launch_bounds__(256) void agg16(const float* __restrict__ T,
                                             const int* __restrict__ row_ptr,
                                             const int* __restrict__ ssrc,
                                             const float* __restrict__ sw,
                                             const float* __restrict__ dis,
                                             const float* __restrict__ bias,
                                             float* __restrict__ out, int N) {
    const int t = blockIdx.x * 256 + threadIdx.x;
    const int node = t >> 4;
    const int f = t & 15;
    if (node >= N) return;
    const float d = dis[node];
    float acc = d * d * T[(size_t)node * 16 + f];
    const int e0 = row_ptr[node], e1 = row_ptr[node + 1];
    for (int e = e0; e < e1; ++e) {
        acc += sw[e] * T[(size_t)ssrc[e] * 16 + f];
    }
    out[(size_t)node * 16 + f] = acc + bias[f];
}

// ---------------- launch ----------------

extern "C" void kernel_launch(void* const* d_in, const int* in_sizes, int n_in,
                              void* d_out, int out_size, void* d_ws, size_t ws_size,
                              hipStream_t stream) {
    const float* x  = (const float*)d_in[0];
    const int*   ei = (const int*)d_in[1];
    const float* W1 = (const float*)d_in[2];
    const float* b1 = (const float*)d_in[3];
    const float* W2 = (const float*)d_in[4];
    const float* b2 = (const float*)d_in[5];
    const float* W3 = (const float*)d_in[6];
    const float* b3 = (const float*)d_in[7];
    float* out = (float*)d_out;

    const int N = in_sizes[0] / NFEAT_IN;   // 50000
    const int E = in_sizes[1] / 2;          // 640000
    const int* src = ei;
    const int* dst = ei + E;

    // workspace carve-up (256B aligned)
    char* p = (char*)d_ws;
    auto alloc = [&](size_t bytes) -> void* {
        void* r = (void*)p;
        p += (bytes + 255) & ~(size_t)255;
        return r;
    };
    int*   cnt     = (int*)alloc((size_t)N * 4);
    int*   row_ptr = (int*)alloc(((size_t)N + 1) * 4);
    int*   cursor  = (int*)alloc((size_t)N * 4);
    float* dis     = (float*)alloc((size_t)N * 4);
    int*   bsum    = (int*)alloc(64 * 4);
    int*   ssrc    = (int*)alloc((size_t)E * 4);
    float* sw      = (float*)alloc((size_t)E * 4);
    float* T       = (float*)alloc((size_t)N * 128 * 4);  // pre-agg transform (also reused for T3)
    float* H       = (float*)alloc((size_t)N * 128 * 4);  // post-agg activations

    hipMemsetAsync(cnt, 0, (size_t)N * 4, stream);
    hipMemsetAsync(cursor, 0, (size_t)N * 4, stream);

    const int eb = (E + 255) / 256;
    const int nchunks = (N + SCAN_CHUNK - 1) / SCAN_CHUNK;   // 25

    count_kernel<<<eb, 256, 0, stream>>>(dst, cnt, E);
    scan_partial<<<nchunks, 256, 0, stream>>>(cnt, bsum, N);
    scan_bsum<<<1, 64, 0, stream>>>(bsum, nchunks);
    scan_final<<<nchunks, 256, 0, stream>>>(cnt, bsum, row_ptr, dis, N);
    fill_kernel<<<eb, 256, 0, stream>>>(src, dst, dis, row_ptr, cursor, ssrc, sw, E);

    const int gemm_blocks = (N + 63) / 64;
    const int agg128_blocks = (N + 3) / 4;     // 4 nodes (waves) per block

    // Layer 1: T = x @ W1 ; H = relu(agg(T) + b1)
    gemm_n128<NFEAT_IN><<<gemm_blocks, 256, 0, stream>>>(x, W1, T, N);
    agg128<<<agg128_blocks, 256, 0, stream>>>(T, row_ptr, ssrc, sw, dis, b1, H, N, 1);

    // Layer 2: T = H @ W2 ; H = relu(agg(T) + b2)
    gemm_n128<HIDDEN><<<gemm_blocks, 256, 0, stream>>>(H, W2, T, N);
    agg128<<<agg128_blocks, 256, 0, stream>>>(T, row_ptr, ssrc, sw, dis, b2, H, N, 1);

    // Layer 3: T3 (reuse T) = H @ W3 ; out = agg(T3) + b3
    gemm_n16<<<(N + 15) / 16, 256, 0, stream>>>(H, W3, T, N);
    agg16<<<(N * 16 + 255) / 256, 256, 0, stream>>>(T, row_ptr, ssrc, sw, dis, b3, out, N);
}

// Round 3
// 379.191 us; speedup vs baseline: 1.3689x; 1.1345x over previous
//
#include <hip/hip_runtime.h>
#include <hip/hip_bf16.h>

// GCN: 3 layers of (X @ W) -> symmetric-normalized neighbor aggregation (+self loop) -> bias -> relu
// N=50000 nodes, E=640000 edges, dims 256 -> 128 -> 128 -> 16, all fp32.
// CSR build per launch (count / 3-kernel scan / fill), pull-aggregation (no atomics in hot path).
// R1: replaced single-block scan (94 us) with 3-kernel device-wide scan (~7 us).
// R2: agg128 was latency-bound (73 us, VALUBusy 13%, 31% HBM): per-edge dependent
//     index->row load chain. Now: one coalesced load grabs 64 edge (idx,w) pairs into
//     lane registers, __shfl broadcasts them, T-row gathers are independent and
//     unrolled x4 (4 x 512B in flight). float2/lane halves load instruction count.

#define NFEAT_IN 256
#define HIDDEN   128
#define NCLS     16
#define SCAN_CHUNK 2048   // elements per block in the scan (256 thr x 8)

// ---------------- CSR build ----------------

__global__ void count_kernel(const int* __restrict__ dst, int* __restrict__ cnt, int E) {
    int e = blockIdx.x * 256 + threadIdx.x;
    if (e < E) atomicAdd(&cnt[dst[e]], 1);
}

// Per-chunk sums. grid = nchunks, block = 256, 8 elements/thread.
__global__ __launch_bounds__(256) void scan_partial(const int* __restrict__ cnt,
                                                    int* __restrict__ bsum, int N) {
    const int t = threadIdx.x;
    const int base = blockIdx.x * SCAN_CHUNK + t * 8;
    int s = 0;
#pragma unroll
    for (int i = 0; i < 8; i++) {
        int idx = base + i;
        if (idx < N) s += cnt[idx];
    }
#pragma unroll
    for (int off = 32; off > 0; off >>= 1) s += __shfl_down(s, off, 64);
    __shared__ int ws[4];
    if ((t & 63) == 0) ws[t >> 6] = s;
    __syncthreads();
    if (t == 0) bsum[blockIdx.x] = ws[0] + ws[1] + ws[2] + ws[3];
}

// Exclusive scan of <=64 chunk sums in place, one wave.
__global__ void scan_bsum(int* __restrict__ bsum, int nb) {
    const int t = threadIdx.x;
    int orig = (t < nb) ? bsum[t] : 0;
    int v = orig;
#pragma unroll
    for (int off = 1; off < 64; off <<= 1) {
        int u = __shfl_up(v, off, 64);
        if (t >= off) v += u;
    }
    if (t < nb) bsum[t] = v - orig;   // exclusive
}

// Per-chunk exclusive scan + chunk offset -> row_ptr. Also writes dis = rsqrt(deg+1).
__global__ __launch_bounds__(256) void scan_final(const int* __restrict__ cnt,
                                                  const int* __restrict__ bsum,
                                                  int* __restrict__ row_ptr,
                                                  float* __restrict__ dis, int N) {
    const int t = threadIdx.x;
    const int base = blockIdx.x * SCAN_CHUNK + t * 8;
    int v[8];
    int s = 0;
#pragma unroll
    for (int i = 0; i < 8; i++) {
        int idx = base + i;
        v[i] = (idx < N) ? cnt[idx] : 0;
        s += v[i];
    }
    __shared__ int sm[256];
    sm[t] = s;
    __syncthreads();
    for (int off = 1; off < 256; off <<= 1) {
        int u = (t >= off) ? sm[t - off] : 0;
        __syncthreads();
        sm[t] += u;
        __syncthreads();
    }
    int run = bsum[blockIdx.x] + ((t == 0) ? 0 : sm[t - 1]);
#pragma unroll
    for (int i = 0; i < 8; i++) {
        int idx = base + i;
        if (idx < N) {
            row_ptr[idx] = run;
            dis[idx] = rsqrtf((float)(v[i] + 1));   // +1 = self loop; deg >= 1 always
            run += v[i];
            if (idx == N - 1) row_ptr[N] = run;     // total edge count
        }
    }
}

__global__ void fill_kernel(const int* __restrict__ src, const int* __restrict__ dst,
                            const float* __restrict__ dis, const int* __restrict__ row_ptr,
                            int* __restrict__ cursor, int* __restrict__ ssrc,
                            float* __restrict__ sw, int E) {
    int e = blockIdx.x * 256 + threadIdx.x;
    if (e >= E) return;
    int s = src[e], d = dst[e];
    int pos = atomicAdd(&cursor[d], 1);
    int idx = row_ptr[d] + pos;
    ssrc[idx] = s;
    sw[idx] = dis[s] * dis[d];
}

// ---------------- GEMM: C[M x 128] = A[M x K] * B[K x 128] ----------------
// BM=64 BN=128 BK=16, 256 threads, thread tile 8x4.

template<int K>
__global__ __launch_bounds__(256) void gemm_n128(const float* __restrict__ A,
                                                 const float* __restrict__ B,
                                                 float* __restrict__ C, int M) {
    constexpr int BM = 64, BN = 128, BK = 16;
    __shared__ float As[BK][BM];   // k-major (transposed on load)
    __shared__ float Bs[BK][BN];
    const int tid = threadIdx.x;
    const int m0 = blockIdx.x * BM;
    const int rg = tid >> 5;          // 0..7 row group (8 rows each)
    const int cg = tid & 31;          // 0..31 col group (4 cols each)
    const int lrow = tid >> 2;        // A-load: row 0..63
    const int lk4  = (tid & 3) * 4;   // A-load: k offset 0/4/8/12

    float acc[8][4] = {};

    for (int kk = 0; kk < K; kk += BK) {
        float4 av = make_float4(0.f, 0.f, 0.f, 0.f);
        if (m0 + lrow < M)
            av = *(const float4*)(A + (size_t)(m0 + lrow) * K + kk + lk4);
        As[lk4 + 0][lrow] = av.x;
        As[lk4 + 1][lrow] = av.y;
        As[lk4 + 2][lrow] = av.z;
        As[lk4 + 3][lrow] = av.w;
#pragma unroll
        for (int t = 0; t < 2; t++) {
            int f4 = tid + t * 256;       // 0..511 float4 id of the 16x128 B tile
            int bk = f4 >> 5;             // 0..15
            int bn = (f4 & 31) * 4;       // 0..124
            float4 bv = *(const float4*)(B + (size_t)(kk + bk) * BN + bn);
            *(float4*)&Bs[bk][bn] = bv;
        }
        __syncthreads();
#pragma unroll
        for (int k = 0; k < BK; k++) {
            float a[8], b[4];
            float4 a0 = *(const float4*)&As[k][rg * 8];
            float4 a1 = *(const float4*)&As[k][rg * 8 + 4];
            float4 bb = *(const float4*)&Bs[k][cg * 4];
            a[0] = a0.x; a[1] = a0.y; a[2] = a0.z; a[3] = a0.w;
            a[4] = a1.x; a[5] = a1.y; a[6] = a1.z; a[7] = a1.w;
            b[0] = bb.x; b[1] = bb.y; b[2] = bb.z; b[3] = bb.w;
#pragma unroll
            for (int i = 0; i < 8; i++)
#pragma unroll
                for (int j = 0; j < 4; j++)
                    acc[i][j] += a[i] * b[j];
        }
        __syncthreads();
    }
#pragma unroll
    for (int i = 0; i < 8; i++) {
        int m = m0 + rg * 8 + i;
        if (m < M)
            *(float4*)(C + (size_t)m * BN + cg * 4) =
                make_float4(acc[i][0], acc[i][1], acc[i][2], acc[i][3]);
    }
}

// GEMM: C[M x 16] = A[M x 128] * B[128 x 16]. 16 rows/block, 256 threads (16x16).
__global__ __launch_bounds__(256) void gemm_n16(const float* __restrict__ A,
                                                const float* __restrict__ B,
                                                float* __restrict__ C, int M) {
    __shared__ float As[16][130];
    __shared__ float Bs[128][16];
    const int tid = threadIdx.x;
    const int m0 = blockIdx.x * 16;
#pragma unroll
    for (int t = 0; t < 2; t++) {
        int f4 = tid + t * 256;   // 0..511 float4 of 16x128 A tile
        int r = f4 >> 5;          // 0..15
        int c4 = (f4 & 31) * 4;
        float4 v = make_float4(0.f, 0.f, 0.f, 0.f);
        if (m0 + r < M) v = *(const float4*)(A + (size_t)(m0 + r) * 128 + c4);
        As[r][c4] = v.x; As[r][c4 + 1] = v.y; As[r][c4 + 2] = v.z; As[r][c4 + 3] = v.w;
        // B tile: 128x16 = 512 float4 as well
        int bk = f4 >> 2;          // 0..127
        int bn = (f4 & 3) * 4;     // 0,4,8,12
        float4 bv = *(const float4*)(B + (size_t)bk * 16 + bn);
        *(float4*)&Bs[bk][bn] = bv;
    }
    __syncthreads();
    const int r = tid >> 4, f = tid & 15;
    float acc = 0.f;
#pragma unroll 8
    for (int k = 0; k < 128; k++) acc += As[r][k] * Bs[k][f];
    if (m0 + r < M) C[(size_t)(m0 + r) * 16 + f] = acc;
}

// ---------------- Aggregation (pull, CSR) ----------------
// One wave per node. Feature map: lane covers feats [2*lane, 2*lane+1] (float2).
// Edge (idx,w) pairs are loaded 64-at-a-time coalesced into lane registers, then
// broadcast via __shfl -> T-row gathers are independent; unrolled x4 for MLP.
__global__ __launch_bounds__(256) void agg128(const float* __restrict__ T,
                                              const int* __restrict__ row_ptr,
                                              const int* __restrict__ ssrc,
                                              const float* __restrict__ sw,
                                              const float* __restrict__ dis,
                                              const float* __restrict__ bias,
                                              float* __restrict__ Hout, int N, int relu) {
    const int node = (blockIdx.x * 256 + threadIdx.x) >> 6;
    const int lane = threadIdx.x & 63;
    if (node >= N) return;
    const float d = dis[node];
    const float self_w = d * d;
    const float2 tself = *(const float2*)(T + (size_t)node * 128 + lane * 2);
    float a0 = self_w * tself.x;
    float a1 = self_w * tself.y;
    const int e0 = row_ptr[node], e1 = row_ptr[node + 1];
    const int cnt = e1 - e0;

    for (int base = 0; base < cnt; base += 64) {
        const int nb = min(64, cnt - base);
        int   idx = 0;
        float w   = 0.f;
        if (lane < nb) {
            idx = ssrc[e0 + base + lane];
            w   = sw[e0 + base + lane];
        }
        int j = 0;
        for (; j + 4 <= nb; j += 4) {
            int s0 = __shfl(idx, j,     64);
            int s1 = __shfl(idx, j + 1, 64);
            int s2 = __shfl(idx, j + 2, 64);
            int s3 = __shfl(idx, j + 3, 64);
            float w0 = __shfl(w, j,     64);
            float w1 = __shfl(w, j + 1, 64);
            float w2 = __shfl(w, j + 2, 64);
            float w3 = __shfl(w, j + 3, 64);
            float2 r0 = *(const float2*)(T + (size_t)s0 * 128 + lane * 2);
            float2 r1 = *(const float2*)(T + (size_t)s1 * 128 + lane * 2);
            float2 r2 = *(const float2*)(T + (size_t)s2 * 128 + lane * 2);
            float2 r3 = *(const float2*)(T + (size_t)s3 * 128 + lane * 2);
            a0 += w0 * r0.x; a1 += w0 * r0.y;
            a0 += w1 * r1.x; a1 += w1 * r1.y;
            a0 += w2 * r2.x; a1 += w2 * r2.y;
            a0 += w3 * r3.x; a1 += w3 * r3.y;
        }
        for (; j < nb; j++) {
            int   s  = __shfl(idx, j, 64);
            float wj = __shfl(w,   j, 64);
            float2 r = *(const float2*)(T + (size_t)s * 128 + lane * 2);
            a0 += wj * r.x; a1 += wj * r.y;
        }
    }
    const float2 bv = *(const float2*)(bias + lane * 2);
    a0 += bv.x;
    a1 += bv.y;
    if (relu) { a0 = fmaxf(a0, 0.f); a1 = fmaxf(a1, 0.f); }
    *(float2*)(Hout + (size_t)node * 128 + lane * 2) = make_float2(a0, a1);
}

// 16 features: one thread per (node, feat).
__global__ void agg16(const float* __restrict__ T,
                      const int* __restrict__ row_ptr,
                      const int* __restrict__ ssrc,
                      const float* __restrict__ sw,
                      const float* __restrict__ dis,
                      const float* __restrict__ bias,
                      float* __restrict__ out, int N) {
    const int t = blockIdx.x * 256 + threadIdx.x;
    const int node = t >> 4;
    const int f = t & 15;
    if (node >= N) return;
    const float d = dis[node];
    float acc = d * d * T[(size_t)node * 16 + f];
    const int e0 = row_ptr[node], e1 = row_ptr[node + 1];
    for (int e = e0; e < e1; ++e) {
        acc += sw[e] * T[(size_t)ssrc[e] * 16 + f];
    }
    out[(size_t)node * 16 + f] = acc + bias[f];
}

// ---------------- launch ----------------

extern "C" void kernel_launch(void* const* d_in, const int* in_sizes, int n_in,
                              void* d_out, int out_size, void* d_ws, size_t ws_size,
                              hipStream_t stream) {
    const float* x  = (const float*)d_in[0];
    const int*   ei = (const int*)d_in[1];
    const float* W1 = (const float*)d_in[2];
    const float* b1 = (const float*)d_in[3];
    const float* W2 = (const float*)d_in[4];
    const float* b2 = (const float*)d_in[5];
    const float* W3 = (const float*)d_in[6];
    const float* b3 = (const float*)d_in[7];
    float* out = (float*)d_out;

    const int N = in_sizes[0] / NFEAT_IN;   // 50000
    const int E = in_sizes[1] / 2;          // 640000
    const int* src = ei;
    const int* dst = ei + E;

    // workspace carve-up (256B aligned)
    char* p = (char*)d_ws;
    auto alloc = [&](size_t bytes) -> void* {
        void* r = (void*)p;
        p += (bytes + 255) & ~(size_t)255;
        return r;
    };
    int*   cnt     = (int*)alloc((size_t)N * 4);
    int*   row_ptr = (int*)alloc(((size_t)N + 1) * 4);
    int*   cursor  = (int*)alloc((size_t)N * 4);
    float* dis     = (float*)alloc((size_t)N * 4);
    int*   bsum    = (int*)alloc(64 * 4);
    int*   ssrc    = (int*)alloc((size_t)E * 4);
    float* sw      = (float*)alloc((size_t)E * 4);
    float* T       = (float*)alloc((size_t)N * 128 * 4);  // pre-agg transform (also reused for T3)
    float* H       = (float*)alloc((size_t)N * 128 * 4);  // post-agg activations

    hipMemsetAsync(cnt, 0, (size_t)N * 4, stream);
    hipMemsetAsync(cursor, 0, (size_t)N * 4, stream);

    const int eb = (E + 255) / 256;
    const int nchunks = (N + SCAN_CHUNK - 1) / SCAN_CHUNK;   // 25

    count_kernel<<<eb, 256, 0, stream>>>(dst, cnt, E);
    scan_partial<<<nchunks, 256, 0, stream>>>(cnt, bsum, N);
    scan_bsum<<<1, 64, 0, stream>>>(bsum, nchunks);
    scan_final<<<nchunks, 256, 0, stream>>>(cnt, bsum, row_ptr, dis, N);
    fill_kernel<<<eb, 256, 0, stream>>>(src, dst, dis, row_ptr, cursor, ssrc, sw, E);

    const int gemm_blocks = (N + 63) / 64;
    const int agg128_blocks = (N + 3) / 4;     // 4 nodes (waves) per block

    // Layer 1: T = x @ W1 ; H = relu(agg(T) + b1)
    gemm_n128<NFEAT_IN><<<gemm_blocks, 256, 0, stream>>>(x, W1, T, N);
    agg128<<<agg128_blocks, 256, 0, stream>>>(T, row_ptr, ssrc, sw, dis, b1, H, N, 1);

    // Layer 2: T = H @ W2 ; H = relu(agg(T) + b2)
    gemm_n128<HIDDEN><<<gemm_blocks, 256, 0, stream>>>(H, W2, T, N);
    agg128<<<agg128_blocks, 256, 0, stream>>>(T, row_ptr, ssrc, sw, dis, b2, H, N, 1);

    // Layer 3: T3 (reuse T) = H @ W3 ; out = agg(T3) + b3
    gemm_n16<<<(N + 15) / 16, 256, 0, stream>>>(H, W3, T, N);
    agg16<<<(N * 16 + 255) / 256, 256, 0, stream>>>(T, row_ptr, ssrc, sw, dis, b3, out, N);
}

// Round 4
// 348.779 us; speedup vs baseline: 1.4883x; 1.0872x over previous
//
#include <hip/hip_runtime.h>
#include <hip/hip_bf16.h>

// GCN: 3 layers of (X @ W) -> symmetric-normalized neighbor aggregation (+self loop) -> bias -> relu
// N=50000 nodes, E=640000 edges, dims 256 -> 128 -> 128 -> 16, all fp32.
// R1: 3-kernel device-wide scan (was 94 us single-block).
// R2: agg128 shfl-broadcast edge batching (73 -> ~30 us, latency fix).
// R3: gemm_n128 was fp32 VALU-bound (VALUBusy 40%, MfmaUtil 0, 51 TF of 157 peak).
//     Now split-precision bf16 MFMA: a = a_hi + a_lo (bf16 each), C = Ah*Bh + Al*Bh + Ah*Bl
//     (fp32 accumulate) -> ~2^-17 effective precision, ~15x compute headroom vs fp32 VALU.
//     A split in-kernel during LDS staging; W pre-split+transposed to Bt[n][k] by prep kernel.

#define NFEAT_IN 256
#define HIDDEN   128
#define NCLS     16
#define SCAN_CHUNK 2048

typedef __attribute__((ext_vector_type(8))) short bf16x8;   // 8 bf16 in 4 VGPRs
typedef __attribute__((ext_vector_type(4))) float f32x4;

#define MFMA16(a, b, c) __builtin_amdgcn_mfma_f32_16x16x32_bf16((a), (b), (c), 0, 0, 0)

// round-to-nearest-even fp32 -> bf16 (bit pattern)
__device__ __forceinline__ unsigned short f2bf(float v) {
    union { float f; unsigned u; } a; a.f = v;
    unsigned r = a.u + 0x7fff + ((a.u >> 16) & 1);
    return (unsigned short)(r >> 16);
}
__device__ __forceinline__ float bf2f(unsigned short h) {
    union { unsigned u; float f; } b; b.u = (unsigned)h << 16;
    return b.f;
}
__device__ __forceinline__ void split1(float v, unsigned short& h, unsigned short& l) {
    h = f2bf(v);
    l = f2bf(v - bf2f(h));
}

// ---------------- CSR build ----------------

__global__ void count_kernel(const int* __restrict__ dst, int* __restrict__ cnt, int E) {
    int e = blockIdx.x * 256 + threadIdx.x;
    if (e < E) atomicAdd(&cnt[dst[e]], 1);
}

__global__ __launch_bounds__(256) void scan_partial(const int* __restrict__ cnt,
                                                    int* __restrict__ bsum, int N) {
    const int t = threadIdx.x;
    const int base = blockIdx.x * SCAN_CHUNK + t * 8;
    int s = 0;
#pragma unroll
    for (int i = 0; i < 8; i++) {
        int idx = base + i;
        if (idx < N) s += cnt[idx];
    }
#pragma unroll
    for (int off = 32; off > 0; off >>= 1) s += __shfl_down(s, off, 64);
    __shared__ int ws[4];
    if ((t & 63) == 0) ws[t >> 6] = s;
    __syncthreads();
    if (t == 0) bsum[blockIdx.x] = ws[0] + ws[1] + ws[2] + ws[3];
}

__global__ void scan_bsum(int* __restrict__ bsum, int nb) {
    const int t = threadIdx.x;
    int orig = (t < nb) ? bsum[t] : 0;
    int v = orig;
#pragma unroll
    for (int off = 1; off < 64; off <<= 1) {
        int u = __shfl_up(v, off, 64);
        if (t >= off) v += u;
    }
    if (t < nb) bsum[t] = v - orig;
}

__global__ __launch_bounds__(256) void scan_final(const int* __restrict__ cnt,
                                                  const int* __restrict__ bsum,
                                                  int* __restrict__ row_ptr,
                                                  float* __restrict__ dis, int N) {
    const int t = threadIdx.x;
    const int base = blockIdx.x * SCAN_CHUNK + t * 8;
    int v[8];
    int s = 0;
#pragma unroll
    for (int i = 0; i < 8; i++) {
        int idx = base + i;
        v[i] = (idx < N) ? cnt[idx] : 0;
        s += v[i];
    }
    __shared__ int sm[256];
    sm[t] = s;
    __syncthreads();
    for (int off = 1; off < 256; off <<= 1) {
        int u = (t >= off) ? sm[t - off] : 0;
        __syncthreads();
        sm[t] += u;
        __syncthreads();
    }
    int run = bsum[blockIdx.x] + ((t == 0) ? 0 : sm[t - 1]);
#pragma unroll
    for (int i = 0; i < 8; i++) {
        int idx = base + i;
        if (idx < N) {
            row_ptr[idx] = run;
            dis[idx] = rsqrtf((float)(v[i] + 1));
            run += v[i];
            if (idx == N - 1) row_ptr[N] = run;
        }
    }
}

__global__ void fill_kernel(const int* __restrict__ src, const int* __restrict__ dst,
                            const float* __restrict__ dis, const int* __restrict__ row_ptr,
                            int* __restrict__ cursor, int* __restrict__ ssrc,
                            float* __restrict__ sw, int E) {
    int e = blockIdx.x * 256 + threadIdx.x;
    if (e >= E) return;
    int s = src[e], d = dst[e];
    int pos = atomicAdd(&cursor[d], 1);
    int idx = row_ptr[d] + pos;
    ssrc[idx] = s;
    sw[idx] = dis[s] * dis[d];
}

// ---------------- W prep: split fp32 W[K x 128] into bf16 hi/lo, transposed to [n][k] ----

__global__ void split_w(const float* __restrict__ W, short* __restrict__ Th,
                        short* __restrict__ Tl, int K) {
    int i = blockIdx.x * 256 + threadIdx.x;   // over K*128
    if (i >= K * 128) return;
    int k = i >> 7, n = i & 127;
    unsigned short h, l;
    split1(W[i], h, l);
    Th[(size_t)n * K + k] = (short)h;
    Tl[(size_t)n * K + k] = (short)l;
}

// ---------------- GEMM (split-bf16 MFMA): C[M x 128] = A[M x K] * B[K x 128] ----------------
// BM=128, BN=128, BK=32; 256 threads = 4 waves; wave = 32 rows (2 m-tiles) x 128 cols (8 n-tiles).
// LDS rows padded to 40 shorts (80 B): frag ds_read_b128 lands 2 lanes/bank = conflict-free.

template<int K>
__global__ __launch_bounds__(256) void gemm_mfma(const float* __restrict__ A,
                                                 const short* __restrict__ Bth,
                                                 const short* __restrict__ Btl,
                                                 float* __restrict__ C, int M) {
    constexpr int BM = 128, BK = 32, LDP = 40;
    __shared__ short Ash[BM][LDP], Asl[BM][LDP];
    __shared__ short Bsh[128][LDP], Bsl[128][LDP];
    const int tid = threadIdx.x;
    const int m0 = blockIdx.x * BM;
    const int w = tid >> 6, lane = tid & 63;
    const int fr = lane & 15, q = lane >> 4;
    const int tr = tid >> 1;            // staging row 0..127
    const int th = (tid & 1) * 16;      // staging col half (elements)

    f32x4 acc[2][8];
    const f32x4 zf = {0.f, 0.f, 0.f, 0.f};
#pragma unroll
    for (int mt = 0; mt < 2; mt++)
#pragma unroll
        for (int nt = 0; nt < 8; nt++) acc[mt][nt] = zf;

    const bool arow_valid = (m0 + tr) < M;
    const float* arow = A + (size_t)(m0 + tr) * K + th;
    const short* bhrow = Bth + (size_t)tr * K + th;
    const short* blrow = Btl + (size_t)tr * K + th;

    for (int kk = 0; kk < K; kk += BK) {
        __syncthreads();   // previous iter's frag reads complete before overwrite
        // ---- stage A (fp32 -> hi/lo bf16) : row tr, cols [kk+th, kk+th+16) ----
        {
            float vv[16];
            if (arow_valid) {
                const float4 v0 = *(const float4*)(arow + kk + 0);
                const float4 v1 = *(const float4*)(arow + kk + 4);
                const float4 v2 = *(const float4*)(arow + kk + 8);
                const float4 v3 = *(const float4*)(arow + kk + 12);
                vv[0] = v0.x; vv[1] = v0.y; vv[2] = v0.z; vv[3] = v0.w;
                vv[4] = v1.x; vv[5] = v1.y; vv[6] = v1.z; vv[7] = v1.w;
                vv[8] = v2.x; vv[9] = v2.y; vv[10] = v2.z; vv[11] = v2.w;
                vv[12] = v3.x; vv[13] = v3.y; vv[14] = v3.z; vv[15] = v3.w;
            } else {
#pragma unroll
                for (int i = 0; i < 16; i++) vv[i] = 0.f;
            }
            unsigned short hb[16], lb[16];
#pragma unroll
            for (int i = 0; i < 16; i++) split1(vv[i], hb[i], lb[i]);
            *(int4*)&Ash[tr][th]     = *(const int4*)&hb[0];
            *(int4*)&Ash[tr][th + 8] = *(const int4*)&hb[8];
            *(int4*)&Asl[tr][th]     = *(const int4*)&lb[0];
            *(int4*)&Asl[tr][th + 8] = *(const int4*)&lb[8];
        }
        // ---- stage B (already bf16, [n][k] layout) ----
        {
            *(int4*)&Bsh[tr][th]     = *(const int4*)(bhrow + kk);
            *(int4*)&Bsh[tr][th + 8] = *(const int4*)(bhrow + kk + 8);
            *(int4*)&Bsl[tr][th]     = *(const int4*)(blrow + kk);
            *(int4*)&Bsl[tr][th + 8] = *(const int4*)(blrow + kk + 8);
        }
        __syncthreads();

        // ---- fragments + MFMA ----
        const int mr = w * 32 + fr;
        bf16x8 ah0 = *(const bf16x8*)&Ash[mr][q * 8];
        bf16x8 ah1 = *(const bf16x8*)&Ash[mr + 16][q * 8];
        bf16x8 al0 = *(const bf16x8*)&Asl[mr][q * 8];
        bf16x8 al1 = *(const bf16x8*)&Asl[mr + 16][q * 8];
#pragma unroll
        for (int nt = 0; nt < 8; nt++) {
            bf16x8 bh = *(const bf16x8*)&Bsh[nt * 16 + fr][q * 8];
            bf16x8 bl = *(const bf16x8*)&Bsl[nt * 16 + fr][q * 8];
            acc[0][nt] = MFMA16(ah0, bh, acc[0][nt]);
            acc[1][nt] = MFMA16(ah1, bh, acc[1][nt]);
            acc[0][nt] = MFMA16(al0, bh, acc[0][nt]);
            acc[1][nt] = MFMA16(al1, bh, acc[1][nt]);
            acc[0][nt] = MFMA16(ah0, bl, acc[0][nt]);
            acc[1][nt] = MFMA16(ah1, bl, acc[1][nt]);
        }
    }

    // ---- store: C/D layout col = lane&15, row = q*4 + reg ----
#pragma unroll
    for (int mt = 0; mt < 2; mt++) {
        const int rowb = m0 + w * 32 + mt * 16 + q * 4;
#pragma unroll
        for (int r = 0; r < 4; r++) {
            const int row = rowb + r;
            if (row < M) {
#pragma unroll
                for (int nt = 0; nt < 8; nt++)
                    C[(size_t)row * 128 + nt * 16 + fr] = acc[mt][nt][r];
            }
        }
    }
}

// GEMM: C[M x 16] = A[M x 128] * B[128 x 16]. 16 rows/block, 256 threads (16x16).
__global__ __launch_bounds__(256) void gemm_n16(const float* __restrict__ A,
                                                const float* __restrict__ B,
                                                float* __restrict__ C, int M) {
    __shared__ float As[16][130];
    __shared__ float Bs[128][16];
    const int tid = threadIdx.x;
    const int m0 = blockIdx.x * 16;
#pragma unroll
    for (int t = 0; t < 2; t++) {
        int f4 = tid + t * 256;
        int r = f4 >> 5;
        int c4 = (f4 & 31) * 4;
        float4 v = make_float4(0.f, 0.f, 0.f, 0.f);
        if (m0 + r < M) v = *(const float4*)(A + (size_t)(m0 + r) * 128 + c4);
        As[r][c4] = v.x; As[r][c4 + 1] = v.y; As[r][c4 + 2] = v.z; As[r][c4 + 3] = v.w;
        int bk = f4 >> 2;
        int bn = (f4 & 3) * 4;
        float4 bv = *(const float4*)(B + (size_t)bk * 16 + bn);
        *(float4*)&Bs[bk][bn] = bv;
    }
    __syncthreads();
    const int r = tid >> 4, f = tid & 15;
    float acc = 0.f;
#pragma unroll 8
    for (int k = 0; k < 128; k++) acc += As[r][k] * Bs[k][f];
    if (m0 + r < M) C[(size_t)(m0 + r) * 16 + f] = acc;
}

// ---------------- Aggregation (pull, CSR) ----------------
__global__ __launch_bounds__(256) void agg128(const float* __restrict__ T,
                                              const int* __restrict__ row_ptr,
                                              const int* __restrict__ ssrc,
                                              const float* __restrict__ sw,
                                              const float* __restrict__ dis,
                                              const float* __restrict__ bias,
                                              float* __restrict__ Hout, int N, int relu) {
    const int node = (blockIdx.x * 256 + threadIdx.x) >> 6;
    const int lane = threadIdx.x & 63;
    if (node >= N) return;
    const float d = dis[node];
    const float self_w = d * d;
    const float2 tself = *(const float2*)(T + (size_t)node * 128 + lane * 2);
    float a0 = self_w * tself.x;
    float a1 = self_w * tself.y;
    const int e0 = row_ptr[node], e1 = row_ptr[node + 1];
    const int cnt = e1 - e0;

    for (int base = 0; base < cnt; base += 64) {
        const int nb = min(64, cnt - base);
        int   idx = 0;
        float w   = 0.f;
        if (lane < nb) {
            idx = ssrc[e0 + base + lane];
            w   = sw[e0 + base + lane];
        }
        int j = 0;
        for (; j + 4 <= nb; j += 4) {
            int s0 = __shfl(idx, j,     64);
            int s1 = __shfl(idx, j + 1, 64);
            int s2 = __shfl(idx, j + 2, 64);
            int s3 = __shfl(idx, j + 3, 64);
            float w0 = __shfl(w, j,     64);
            float w1 = __shfl(w, j + 1, 64);
            float w2 = __shfl(w, j + 2, 64);
            float w3 = __shfl(w, j + 3, 64);
            float2 r0 = *(const float2*)(T + (size_t)s0 * 128 + lane * 2);
            float2 r1 = *(const float2*)(T + (size_t)s1 * 128 + lane * 2);
            float2 r2 = *(const float2*)(T + (size_t)s2 * 128 + lane * 2);
            float2 r3 = *(const float2*)(T + (size_t)s3 * 128 + lane * 2);
            a0 += w0 * r0.x; a1 += w0 * r0.y;
            a0 += w1 * r1.x; a1 += w1 * r1.y;
            a0 += w2 * r2.x; a1 += w2 * r2.y;
            a0 += w3 * r3.x; a1 += w3 * r3.y;
        }
        for (; j < nb; j++) {
            int   s  = __shfl(idx, j, 64);
            float wj = __shfl(w,   j, 64);
            float2 r = *(const float2*)(T + (size_t)s * 128 + lane * 2);
            a0 += wj * r.x; a1 += wj * r.y;
        }
    }
    const float2 bv = *(const float2*)(bias + lane * 2);
    a0 += bv.x;
    a1 += bv.y;
    if (relu) { a0 = fmaxf(a0, 0.f); a1 = fmaxf(a1, 0.f); }
    *(float2*)(Hout + (size_t)node * 128 + lane * 2) = make_float2(a0, a1);
}

__global__ void agg16(const float* __restrict__ T,
                      const int* __restrict__ row_ptr,
                      const int* __restrict__ ssrc,
                      const float* __restrict__ sw,
                      const float* __restrict__ dis,
                      const float* __restrict__ bias,
                      float* __restrict__ out, int N) {
    const int t = blockIdx.x * 256 + threadIdx.x;
    const int node = t >> 4;
    const int f = t & 15;
    if (node >= N) return;
    const float d = dis[node];
    float acc = d * d * T[(size_t)node * 16 + f];
    const int e0 = row_ptr[node], e1 = row_ptr[node + 1];
    for (int e = e0; e < e1; ++e) {
        acc += sw[e] * T[(size_t)ssrc[e] * 16 + f];
    }
    out[(size_t)node * 16 + f] = acc + bias[f];
}

// ---------------- launch ----------------

extern "C" void kernel_launch(void* const* d_in, const int* in_sizes, int n_in,
                              void* d_out, int out_size, void* d_ws, size_t ws_size,
                              hipStream_t stream) {
    const float* x  = (const float*)d_in[0];
    const int*   ei = (const int*)d_in[1];
    const float* W1 = (const float*)d_in[2];
    const float* b1 = (const float*)d_in[3];
    const float* W2 = (const float*)d_in[4];
    const float* b2 = (const float*)d_in[5];
    const float* W3 = (const float*)d_in[6];
    const float* b3 = (const float*)d_in[7];
    float* out = (float*)d_out;

    const int N = in_sizes[0] / NFEAT_IN;   // 50000
    const int E = in_sizes[1] / 2;          // 640000
    const int* src = ei;
    const int* dst = ei + E;

    char* p = (char*)d_ws;
    auto alloc = [&](size_t bytes) -> void* {
        void* r = (void*)p;
        p += (bytes + 255) & ~(size_t)255;
        return r;
    };
    int*   cnt     = (int*)alloc((size_t)N * 4);
    int*   row_ptr = (int*)alloc(((size_t)N + 1) * 4);
    int*   cursor  = (int*)alloc((size_t)N * 4);
    float* dis     = (float*)alloc((size_t)N * 4);
    int*   bsum    = (int*)alloc(64 * 4);
    int*   ssrc    = (int*)alloc((size_t)E * 4);
    float* sw      = (float*)alloc((size_t)E * 4);
    short* Bt1h    = (short*)alloc((size_t)NFEAT_IN * 128 * 2);
    short* Bt1l    = (short*)alloc((size_t)NFEAT_IN * 128 * 2);
    short* Bt2h    = (short*)alloc((size_t)HIDDEN * 128 * 2);
    short* Bt2l    = (short*)alloc((size_t)HIDDEN * 128 * 2);
    float* T       = (float*)alloc((size_t)N * 128 * 4);
    float* H       = (float*)alloc((size_t)N * 128 * 4);

    hipMemsetAsync(cnt, 0, (size_t)N * 4, stream);
    hipMemsetAsync(cursor, 0, (size_t)N * 4, stream);

    const int eb = (E + 255) / 256;
    const int nchunks = (N + SCAN_CHUNK - 1) / SCAN_CHUNK;

    count_kernel<<<eb, 256, 0, stream>>>(dst, cnt, E);
    scan_partial<<<nchunks, 256, 0, stream>>>(cnt, bsum, N);
    scan_bsum<<<1, 64, 0, stream>>>(bsum, nchunks);
    scan_final<<<nchunks, 256, 0, stream>>>(cnt, bsum, row_ptr, dis, N);
    fill_kernel<<<eb, 256, 0, stream>>>(src, dst, dis, row_ptr, cursor, ssrc, sw, E);

    // W prep (tiny): split + transpose
    split_w<<<(NFEAT_IN * 128 + 255) / 256, 256, 0, stream>>>(W1, Bt1h, Bt1l, NFEAT_IN);
    split_w<<<(HIDDEN * 128 + 255) / 256, 256, 0, stream>>>(W2, Bt2h, Bt2l, HIDDEN);

    const int gemm_blocks = (N + 127) / 128;
    const int agg128_blocks = (N + 3) / 4;

    // Layer 1
    gemm_mfma<NFEAT_IN><<<gemm_blocks, 256, 0, stream>>>(x, Bt1h, Bt1l, T, N);
    agg128<<<agg128_blocks, 256, 0, stream>>>(T, row_ptr, ssrc, sw, dis, b1, H, N, 1);

    // Layer 2
    gemm_mfma<HIDDEN><<<gemm_blocks, 256, 0, stream>>>(H, Bt2h, Bt2l, T, N);
    agg128<<<agg128_blocks, 256, 0, stream>>>(T, row_ptr, ssrc, sw, dis, b2, H, N, 1);

    // Layer 3
    gemm_n16<<<(N + 15) / 16, 256, 0, stream>>>(H, W3, T, N);
    agg16<<<(N * 16 + 255) / 256, 256, 0, stream>>>(T, row_ptr, ssrc, sw, dis, b3, out, N);
}